// Round 9
// baseline (2571.994 us; speedup 1.0000x reference)
//
#include <hip/hip_runtime.h>
#include <hip/hip_fp16.h>

#define HW 17
#define NPIX 289

typedef float f2 __attribute__((ext_vector_type(2)));
typedef __fp16 h2v __attribute__((ext_vector_type(2)));

__device__ __forceinline__ float bperm(int a, float v) {
    return __int_as_float(__builtin_amdgcn_ds_bpermute(a, __float_as_int(v)));
}
__device__ __forceinline__ float max3f(float a, float b, float c){ return fmaxf(fmaxf(a,b),c); }
__device__ __forceinline__ float clampf(float v){ return fminf(fmaxf(v,-10.f),10.f); }
__device__ __forceinline__ f2 mk2(float s){ return (f2){s,s}; }
__device__ __forceinline__ unsigned h2u(__half2 h){ union{__half2 h; unsigned u;} v; v.h=h; return v.u; }
__device__ __forceinline__ __half2 u2h(unsigned u){ union{__half2 h; unsigned u;} v; v.u=u; return v.h; }
__device__ __forceinline__ unsigned packrtz(float a, float b){
    union{h2v h; unsigned u;} v; v.h = __builtin_amdgcn_cvt_pkrtz(a, b); return v.u;
}

#define EL(A,c) (A[(c)>>1][(c)&1])

// Build sobel column windows (vertical sum v, diff d) for one channel over a
// pair-chunk, carrying the last needed column's v/d in (vL,dL) across chunks.
// Uses CP0/NC declared by the enclosing CA_CHUNK. Columns >16 are literal 0.
#define SOBWIN(XA, vL, dL, sxp, syp)                                          \
    {                                                                         \
        float v[2*NC+2], d[2*NC+2];                                           \
        v[0] = (vL); d[0] = (dL);                                             \
        _Pragma("unroll")                                                     \
        for (int i = 1; i < 2*NC+2; ++i) {                                    \
            const int c = 2*CP0 - 1 + i;                                      \
            if (c <= 16) {                                                    \
                const float xv = EL(XA, c);                                   \
                const float u_ = bperm(upA, xv), dn_ = bperm(dnA, xv);        \
                v[i] = u_ + 2.f*xv + dn_; d[i] = dn_ - u_;                    \
            } else { v[i] = 0.f; d[i] = 0.f; }                                \
        }                                                                     \
        (vL) = v[2*NC]; (dL) = d[2*NC];                                       \
        _Pragma("unroll")                                                     \
        for (int q = 0; q < NC; ++q) {                                        \
            sxp[q] = (f2){ 0.125f*(v[2*q+2]-v[2*q]),                          \
                           0.125f*(v[2*q+3]-v[2*q+1]) };                      \
            syp[q] = (f2){ 0.125f*(d[2*q] + 2.f*d[2*q+1] + d[2*q+2]),         \
                           0.125f*(d[2*q+1] + 2.f*d[2*q+2] + d[2*q+3]) };     \
        }                                                                     \
    }

// One pair-chunk: sobel windows + packed dense (12->16 relu ->4) + in-place
// state update. Pairs jp in [P0_,P1_) cover columns 2*jp, 2*jp+1.
// Per-lane fp16 constants (scent, scent-sobel) live in LDS private slots.
// ch3 (xn3, UNGATED) is packed to fp16 in X3h; its gate is deferred to the end.
#define CA_CHUNK(P0_, P1_)                                                    \
{                                                                             \
    constexpr int CP0 = (P0_);                                                \
    constexpr int NC  = (P1_) - (P0_);                                        \
    f2 sxp0[NC], syp0[NC], sxp1[NC], syp1[NC], sxp2[NC], syp2[NC];            \
    SOBWIN(X0, vL0, dL0, sxp0, syp0)                                          \
    SOBWIN(X1, vL1, dL1, sxp1, syp1)                                          \
    SOBWIN(X2, vL2, dL2, sxp2, syp2)                                          \
    f2 scl[NC], s3x[NC], s3y[NC];                                             \
    _Pragma("unroll")                                                         \
    for (int q = 0; q < NC; ++q) {                                            \
        const int jp = CP0 + q;                                               \
        const float2 sf = __half22float2(u2h(ldsP[lb + 17 + jp]));            \
        scl[q] = (f2){ sf.x, sf.y };                                          \
        const float2 a = __half22float2(u2h(ldsP[lb + 2*jp]));                \
        if (2*jp + 1 <= 16) {                                                 \
            const float2 bq = __half22float2(u2h(ldsP[lb + 2*jp + 1]));       \
            s3x[q] = (f2){ a.x, bq.x }; s3y[q] = (f2){ a.y, bq.y };           \
        } else {                                                              \
            s3x[q] = (f2){ a.x, 0.f }; s3y[q] = (f2){ a.y, 0.f };             \
        }                                                                     \
    }                                                                         \
    f2 dacc0[NC], dacc1[NC], dacc2[NC], dacc3[NC];                            \
    _Pragma("unroll")                                                         \
    for (int q = 0; q < NC; ++q) {                                            \
        dacc0[q] = mk2(b4[0]); dacc1[q] = mk2(b4[1]);                         \
        dacc2[q] = mk2(b4[2]); dacc3[q] = mk2(b4[3]);                         \
    }                                                                         \
    _Pragma("clang loop unroll_count(2)")                                     \
    for (int o = 0; o < 16; ++o) {                                            \
        const float wx0 = w3[o*12+0], wx1 = w3[o*12+1], wx2 = w3[o*12+2], wx3 = w3[o*12+3]; \
        const float wa0 = w3[o*12+4], wa1 = w3[o*12+5], wa2 = w3[o*12+6], wa3 = w3[o*12+7]; \
        const float wb0 = w3[o*12+8], wb1 = w3[o*12+9], wb2 = w3[o*12+10], wb3 = w3[o*12+11]; \
        const float bo = b3[o];                                               \
        const float u0 = w4[o], u1 = w4[16+o], u2 = w4[32+o], u3 = w4[48+o];  \
        _Pragma("unroll")                                                     \
        for (int q = 0; q < NC; ++q) {                                        \
            const int jp = CP0 + q;                                           \
            f2 h = mk2(bo);                                                   \
            h += mk2(wx0) * X0[jp];  h += mk2(wx1) * X1[jp];                  \
            h += mk2(wx2) * X2[jp];  h += mk2(wx3) * scl[q];                  \
            h += mk2(wa0) * sxp0[q]; h += mk2(wa1) * sxp1[q];                 \
            h += mk2(wa2) * sxp2[q]; h += mk2(wa3) * s3x[q];                  \
            h += mk2(wb0) * syp0[q]; h += mk2(wb1) * syp1[q];                 \
            h += mk2(wb2) * syp2[q]; h += mk2(wb3) * s3y[q];                  \
            h.x = fmaxf(h.x, 0.f); h.y = fmaxf(h.y, 0.f);                     \
            dacc0[q] += mk2(u0) * h; dacc1[q] += mk2(u1) * h;                 \
            dacc2[q] += mk2(u2) * h; dacc3[q] += mk2(u3) * h;                 \
        }                                                                     \
    }                                                                         \
    _Pragma("unroll")                                                         \
    for (int q = 0; q < NC; ++q) {                                            \
        const int jp = CP0 + q;                                               \
        X0[jp] = (X0[jp] + dacc0[q]) * am2;                                   \
        X1[jp] = (X1[jp] + dacc1[q]) * am2;                                   \
        X2[jp] = (X2[jp] + dacc2[q]) * am2;                                   \
        X3h[jp] = packrtz(scl[q].x + dacc3[q].x, scl[q].y + dacc3[q].y);      \
    }                                                                         \
}

__global__ __launch_bounds__(256, 4)
void ca_kernel(const float* __restrict__ cell, const float* __restrict__ food,
               const float* __restrict__ w3, const float* __restrict__ b3,
               const float* __restrict__ w4, const float* __restrict__ b4,
               const int* __restrict__ steps_p, const int B,
               float* __restrict__ out_cell, float* __restrict__ out_food,
               float* __restrict__ out_cnt, float* __restrict__ out_abv)
{
    // per-thread private constant slots: 17 words sxy (half2) + 9 words sc
    // (half2 pairs), stride 29 (odd -> bank-conflict-free), no barrier needed
    __shared__ unsigned ldsP[256 * 29];
    const int t    = threadIdx.x;
    const int lb   = t * 29;
    const int lane = t & 63;
    const int wid  = blockIdx.x * (blockDim.x >> 6) + (t >> 6);
    const int bl   = lane / 17;                // 0..2 real, 3 dead
    const int r    = lane - bl * 17;
    const int batch = wid * 3 + bl;
    const bool active = (bl < 3) && (batch < B);
    const float am = active ? 1.f : 0.f;
    const f2 am2 = mk2(am);

    // vertical-neighbor shuffle addresses; out-of-range -> lane 63 (always zero)
    const int upA  = ((r >= 1)            ? (lane - 1) : 63) << 2;
    const int dnA  = ((r <= 15 && bl < 3) ? (lane + 1) : 63) << 2;
    const int up2A = ((r >= 2)            ? (lane - 2) : 63) << 2;
    const int dn2A = ((r <= 14 && bl < 3) ? (lane + 2) : 63) << 2;

    // ---- food load + copy-out ----
    const size_t fbase = (size_t)(active ? batch : 0) * NPIX + (size_t)r * HW;
    float f[HW];
    #pragma unroll
    for (int c = 0; c < HW; ++c) f[c] = active ? food[fbase + c] : 0.f;
    #pragma unroll
    for (int c = 0; c < HW; ++c) if (active) out_food[fbase + c] = f[c];

    // ---- scent (fp32), then pack to fp16 in LDS; scent-sobel likewise ----
    {
        float hf[HW];
        #pragma unroll
        for (int c = 0; c < HW; ++c) {
            float s = f[c];
            if (c >= 1)  s += 0.5f  * f[c - 1];
            if (c <= 15) s += 0.5f  * f[c + 1];
            if (c >= 2)  s += 0.25f * f[c - 2];
            if (c <= 14) s += 0.25f * f[c + 2];
            hf[c] = s;
        }
        float sc[HW];
        {
            float fu2[HW], fd2[HW];
            #pragma unroll
            for (int c = 0; c < HW; ++c) {
                float u1 = bperm(upA, hf[c]),  d1 = bperm(dnA, hf[c]);
                float u2 = bperm(up2A, hf[c]), d2 = bperm(dn2A, hf[c]);
                sc[c] = hf[c] + 0.5f * (u1 + d1) + 0.25f * (u2 + d2);
                fu2[c] = bperm(up2A, f[c]);
                fd2[c] = bperm(dn2A, f[c]);
            }
            #pragma unroll
            for (int c = 0; c < HW; ++c) {
                float corr = 0.f;
                if (c >= 2)  corr += fu2[c - 2] + fd2[c - 2];
                if (c <= 14) corr += fu2[c + 2] + fd2[c + 2];
                sc[c] = (sc[c] - 0.0625f * corr) * am;   // dead lanes exactly 0
            }
        }
        {
            float vS[HW + 2], dS[HW + 2];
            vS[0] = 0.f; vS[HW + 1] = 0.f; dS[0] = 0.f; dS[HW + 1] = 0.f;
            #pragma unroll
            for (int c = 0; c < HW; ++c) {
                float u = bperm(upA, sc[c]), d = bperm(dnA, sc[c]);
                vS[c + 1] = u + 2.f * sc[c] + d;
                dS[c + 1] = d - u;
            }
            #pragma unroll
            for (int c = 0; c < HW; ++c) {
                float sx3 = 0.125f * (vS[c + 2] - vS[c]);
                float sy3 = 0.125f * (dS[c] + 2.f * dS[c + 1] + dS[c + 2]);
                ldsP[lb + c] = h2u(__floats2half2_rn(sx3, sy3));
            }
        }
        #pragma unroll
        for (int i = 0; i < 9; ++i)
            ldsP[lb + 17 + i] =
                h2u(__floats2half2_rn(sc[2 * i], (2 * i + 1 < HW) ? sc[2 * i + 1] : 0.f));
    }

    // ---- initial state as column pairs; column 17 is a phantom zero.
    //      ch3 is not persistent fp32 state: X3h holds last UNGATED xn3 (fp16
    //      packed), Lmask the last life mask; gate applied after the loop. ----
    const size_t cb = (size_t)(active ? batch : 0) * (4 * NPIX) + (size_t)r * HW;
    f2 X0[9], X1[9], X2[9];
    unsigned X3h[9];
    unsigned Lmask = 0u;
    #pragma unroll
    for (int c = 0; c < HW; ++c) {
        EL(X0, c) = active ? cell[cb + c] : 0.f;
        EL(X1, c) = active ? cell[cb + NPIX + c] : 0.f;
        EL(X2, c) = active ? cell[cb + 2 * NPIX + c] : 0.f;
    }
    X0[8].y = 0.f; X1[8].y = 0.f; X2[8].y = 0.f;
    #pragma unroll
    for (int i = 0; i < 9; ++i) X3h[i] = 0u;

    const int steps = steps_p[0];
    for (int s = 0; s < steps; ++s) {
        // ---- premask: maxpool3(x0) > 0.1 as 17-bit per-lane mask ----
        unsigned pmask = 0u;
        {
            float rm[HW];
            #pragma unroll
            for (int c = 0; c < HW; ++c) {
                float a  = (c >= 1)  ? EL(X0, c - 1) : 0.f;
                float b2 = (c <= 15) ? EL(X0, c + 1) : 0.f;
                rm[c] = max3f(a, EL(X0, c), b2);
            }
            #pragma unroll
            for (int c = 0; c < HW; ++c) {
                float pm = max3f(rm[c], bperm(upA, rm[c]), bperm(dnA, rm[c]));
                pmask |= (pm > 0.1f) ? (1u << c) : 0u;
            }
        }

        // ---- sobel + packed dense + update, five pair-chunks (NC=2) ----
        float vL0 = 0.f, dL0 = 0.f, vL1 = 0.f, dL1 = 0.f, vL2 = 0.f, dL2 = 0.f;
        CA_CHUNK(0, 2)
        CA_CHUNK(2, 4)
        CA_CHUNK(4, 6)
        CA_CHUNK(6, 8)
        CA_CHUNK(8, 9)
        X0[8].y = 0.f; X1[8].y = 0.f; X2[8].y = 0.f;  // phantom col

        // ---- post maxpool on ungated xn0 + life gate (ch0..2 only) ----
        {
            float rm[HW];
            #pragma unroll
            for (int c = 0; c < HW; ++c) {
                float a  = (c >= 1)  ? EL(X0, c - 1) : 0.f;
                float b2 = (c <= 15) ? EL(X0, c + 1) : 0.f;
                rm[c] = max3f(a, EL(X0, c), b2);     // dead lanes: X0 masked 0
            }
            unsigned lm = 0u;
            #pragma unroll
            for (int c = 0; c < HW; ++c) {
                float pm = max3f(rm[c], bperm(upA, rm[c]), bperm(dnA, rm[c]));
                const bool L = ((pmask & (1u << c)) != 0u) && (pm > 0.1f);
                lm |= L ? (1u << c) : 0u;
                EL(X0, c) = L ? clampf(EL(X0, c)) : 0.f;
                EL(X1, c) = L ? clampf(EL(X1, c)) : 0.f;
                EL(X2, c) = L ? clampf(EL(X2, c)) : 0.f;
            }
            Lmask = lm;
        }
    }

    // ---- final outputs ----
    #pragma unroll
    for (int c = 0; c < HW; ++c) {
        if (active) {
            out_cell[cb + c]            = EL(X0, c);
            out_cell[cb + NPIX + c]     = EL(X1, c);
            out_cell[cb + 2 * NPIX + c] = EL(X2, c);
            float x3v;
            if (steps == 0) {
                x3v = cell[cb + 3 * NPIX + c];
            } else {
                const float2 p = __half22float2(u2h(X3h[c >> 1]));
                const float raw = (c & 1) ? p.y : p.x;
                x3v = ((Lmask >> c) & 1u) ? clampf(raw) : 0.f;
            }
            out_cell[cb + 3 * NPIX + c] = x3v;
        }
    }

    float rs = 0.f, rc = 0.f;
    #pragma unroll
    for (int c = 0; c < HW; ++c) {
        const float v = EL(X0, c);
        rs += v;
        rc += (v > 0.1f) ? 1.f : 0.f;
    }
    float ssum = rs, scnt = rc;
    for (int k = 1; k <= 16; ++k) {
        int a = ((lane + k) & 63) << 2;
        ssum += bperm(a, rs);
        scnt += bperm(a, rc);
    }
    if (active && r == 0) { out_cnt[batch] = ssum; out_abv[batch] = scnt; }
}

extern "C" void kernel_launch(void* const* d_in, const int* in_sizes, int n_in,
                              void* d_out, int out_size, void* d_ws, size_t ws_size,
                              hipStream_t stream) {
    const float* cell  = (const float*)d_in[0];
    const float* food  = (const float*)d_in[1];
    const float* w3    = (const float*)d_in[2];
    const float* b3    = (const float*)d_in[3];
    const float* w4    = (const float*)d_in[4];
    const float* b4    = (const float*)d_in[5];
    const int*   steps = (const int*)d_in[6];

    const int B = in_sizes[0] / (4 * NPIX);

    float* out      = (float*)d_out;
    float* out_cell = out;
    float* out_food = out      + (size_t)B * 4 * NPIX;
    float* out_cnt  = out_food + (size_t)B * NPIX;
    float* out_abv  = out_cnt  + (size_t)B;

    const int waves  = (B + 2) / 3;
    const int blocks = (waves + 3) / 4;
    hipLaunchKernelGGL(ca_kernel, dim3(blocks), dim3(256), 0, stream,
                       cell, food, w3, b3, w4, b4, steps, B,
                       out_cell, out_food, out_cnt, out_abv);
}

// Round 10
// 2210.305 us; speedup vs baseline: 1.1636x; 1.1636x over previous
//
#include <hip/hip_runtime.h>
#include <hip/hip_fp16.h>

#define HW 17
#define NPIX 289
#define LSTRIDE 39
#define LOFF_SXY 0
#define LOFF_SC  17
#define LOFF_X3  26

typedef float f2 __attribute__((ext_vector_type(2)));
typedef __fp16 h2v __attribute__((ext_vector_type(2)));

__device__ __forceinline__ float bperm(int a, float v) {
    return __int_as_float(__builtin_amdgcn_ds_bpermute(a, __float_as_int(v)));
}
__device__ __forceinline__ float max3f(float a, float b, float c){ return fmaxf(fmaxf(a,b),c); }
__device__ __forceinline__ float clampf(float v){ return __builtin_amdgcn_fmed3f(v, -10.f, 10.f); }
__device__ __forceinline__ f2 mk2(float s){ return (f2){s,s}; }
__device__ __forceinline__ unsigned h2u(__half2 h){ union{__half2 h; unsigned u;} v; v.h=h; return v.u; }
__device__ __forceinline__ __half2 u2h(unsigned u){ union{__half2 h; unsigned u;} v; v.u=u; return v.h; }
__device__ __forceinline__ unsigned packrtz(float a, float b){
    union{h2v h; unsigned u;} v; v.h = __builtin_amdgcn_cvt_pkrtz(a, b); return v.u;
}

#define EL(A,c) (A[(c)>>1][(c)&1])

// Sobel column windows (vertical sum v, diff d) for one channel over a
// pair-chunk; carries last needed column's v/d in (vL,dL). Cols >16 are 0.
#define SOBWIN(XA, vL, dL, sxp, syp)                                          \
    {                                                                         \
        float v[2*NC+2], d[2*NC+2];                                           \
        v[0] = (vL); d[0] = (dL);                                             \
        _Pragma("unroll")                                                     \
        for (int i = 1; i < 2*NC+2; ++i) {                                    \
            const int c = 2*CP0 - 1 + i;                                      \
            if (c <= 16) {                                                    \
                const float xv = EL(XA, c);                                   \
                const float u_ = bperm(upA, xv), dn_ = bperm(dnA, xv);        \
                v[i] = u_ + 2.f*xv + dn_; d[i] = dn_ - u_;                    \
            } else { v[i] = 0.f; d[i] = 0.f; }                                \
        }                                                                     \
        (vL) = v[2*NC]; (dL) = d[2*NC];                                       \
        _Pragma("unroll")                                                     \
        for (int q = 0; q < NC; ++q) {                                        \
            sxp[q] = (f2){ 0.125f*(v[2*q+2]-v[2*q]),                          \
                           0.125f*(v[2*q+3]-v[2*q+1]) };                      \
            syp[q] = (f2){ 0.125f*(d[2*q] + 2.f*d[2*q+1] + d[2*q+2]),         \
                           0.125f*(d[2*q+1] + 2.f*d[2*q+2] + d[2*q+3]) };     \
        }                                                                     \
    }

// Load per-lane fp16 constants for pair jp from private LDS slots.
#define LOAD_CONST(q, jp)                                                     \
        const float2 sf = __half22float2(u2h(ldsP[lb + LOFF_SC + (jp)]));     \
        scl[q] = (f2){ sf.x, sf.y };                                          \
        {                                                                     \
            const float2 a_ = __half22float2(u2h(ldsP[lb + LOFF_SXY + 2*(jp)])); \
            if (2*(jp) + 1 <= 16) {                                           \
                const float2 b_ = __half22float2(u2h(ldsP[lb + LOFF_SXY + 2*(jp) + 1])); \
                s3x[q] = (f2){ a_.x, b_.x }; s3y[q] = (f2){ a_.y, b_.y };     \
            } else {                                                          \
                s3x[q] = (f2){ a_.x, 0.f }; s3y[q] = (f2){ a_.y, 0.f };       \
            }                                                                 \
        }

// Main pair-chunk: sobel + packed dense (ch0..2 ONLY — ch3 is dead in the
// hot loop, handled once on the final step) + in-place state update.
#define CA_CHUNK(P0_, P1_)                                                    \
{                                                                             \
    constexpr int CP0 = (P0_);                                                \
    constexpr int NC  = (P1_) - (P0_);                                        \
    f2 sxp0[NC], syp0[NC], sxp1[NC], syp1[NC], sxp2[NC], syp2[NC];            \
    SOBWIN(X0, vL0, dL0, sxp0, syp0)                                          \
    SOBWIN(X1, vL1, dL1, sxp1, syp1)                                          \
    SOBWIN(X2, vL2, dL2, sxp2, syp2)                                          \
    f2 scl[NC], s3x[NC], s3y[NC];                                             \
    _Pragma("unroll")                                                         \
    for (int q = 0; q < NC; ++q) { LOAD_CONST(q, CP0 + q) }                   \
    f2 dacc0[NC], dacc1[NC], dacc2[NC];                                       \
    _Pragma("unroll")                                                         \
    for (int q = 0; q < NC; ++q) {                                            \
        dacc0[q] = mk2(b4[0]); dacc1[q] = mk2(b4[1]); dacc2[q] = mk2(b4[2]);  \
    }                                                                         \
    _Pragma("clang loop unroll_count(2)")                                     \
    for (int o = 0; o < 16; ++o) {                                            \
        const float wx0 = w3[o*12+0], wx1 = w3[o*12+1], wx2 = w3[o*12+2], wx3 = w3[o*12+3]; \
        const float wa0 = w3[o*12+4], wa1 = w3[o*12+5], wa2 = w3[o*12+6], wa3 = w3[o*12+7]; \
        const float wb0 = w3[o*12+8], wb1 = w3[o*12+9], wb2 = w3[o*12+10], wb3 = w3[o*12+11]; \
        const float bo = b3[o];                                               \
        const float u0 = w4[o], u1 = w4[16+o], u2 = w4[32+o];                 \
        _Pragma("unroll")                                                     \
        for (int q = 0; q < NC; ++q) {                                        \
            const int jp = CP0 + q;                                           \
            f2 h = mk2(bo);                                                   \
            h += mk2(wx0) * X0[jp];  h += mk2(wx1) * X1[jp];                  \
            h += mk2(wx2) * X2[jp];  h += mk2(wx3) * scl[q];                  \
            h += mk2(wa0) * sxp0[q]; h += mk2(wa1) * sxp1[q];                 \
            h += mk2(wa2) * sxp2[q]; h += mk2(wa3) * s3x[q];                  \
            h += mk2(wb0) * syp0[q]; h += mk2(wb1) * syp1[q];                 \
            h += mk2(wb2) * syp2[q]; h += mk2(wb3) * s3y[q];                  \
            h.x = fmaxf(h.x, 0.f); h.y = fmaxf(h.y, 0.f);                     \
            dacc0[q] += mk2(u0) * h; dacc1[q] += mk2(u1) * h;                 \
            dacc2[q] += mk2(u2) * h;                                          \
        }                                                                     \
    }                                                                         \
    _Pragma("unroll")                                                         \
    for (int q = 0; q < NC; ++q) {                                            \
        const int jp = CP0 + q;                                               \
        X0[jp] = (X0[jp] + dacc0[q]) * am2;                                   \
        X1[jp] = (X1[jp] + dacc1[q]) * am2;                                   \
        X2[jp] = (X2[jp] + dacc2[q]) * am2;                                   \
    }                                                                         \
}

// ch3-only pass (final step, BEFORE the state update): full h chain but only
// dacc3; ungated xn3 packed to private LDS. Runs once per kernel.
#define CH3_CHUNK(P0_, P1_)                                                   \
{                                                                             \
    constexpr int CP0 = (P0_);                                                \
    constexpr int NC  = (P1_) - (P0_);                                        \
    f2 sxp0[NC], syp0[NC], sxp1[NC], syp1[NC], sxp2[NC], syp2[NC];            \
    SOBWIN(X0, wL0, eL0, sxp0, syp0)                                          \
    SOBWIN(X1, wL1, eL1, sxp1, syp1)                                          \
    SOBWIN(X2, wL2, eL2, sxp2, syp2)                                          \
    f2 scl[NC], s3x[NC], s3y[NC];                                             \
    _Pragma("unroll")                                                         \
    for (int q = 0; q < NC; ++q) { LOAD_CONST(q, CP0 + q) }                   \
    f2 dacc3[NC];                                                             \
    _Pragma("unroll")                                                         \
    for (int q = 0; q < NC; ++q) dacc3[q] = mk2(b4[3]);                       \
    for (int o = 0; o < 16; ++o) {                                            \
        const float wx0 = w3[o*12+0], wx1 = w3[o*12+1], wx2 = w3[o*12+2], wx3 = w3[o*12+3]; \
        const float wa0 = w3[o*12+4], wa1 = w3[o*12+5], wa2 = w3[o*12+6], wa3 = w3[o*12+7]; \
        const float wb0 = w3[o*12+8], wb1 = w3[o*12+9], wb2 = w3[o*12+10], wb3 = w3[o*12+11]; \
        const float bo = b3[o];                                               \
        const float u3 = w4[48+o];                                            \
        _Pragma("unroll")                                                     \
        for (int q = 0; q < NC; ++q) {                                        \
            const int jp = CP0 + q;                                           \
            f2 h = mk2(bo);                                                   \
            h += mk2(wx0) * X0[jp];  h += mk2(wx1) * X1[jp];                  \
            h += mk2(wx2) * X2[jp];  h += mk2(wx3) * scl[q];                  \
            h += mk2(wa0) * sxp0[q]; h += mk2(wa1) * sxp1[q];                 \
            h += mk2(wa2) * sxp2[q]; h += mk2(wa3) * s3x[q];                  \
            h += mk2(wb0) * syp0[q]; h += mk2(wb1) * syp1[q];                 \
            h += mk2(wb2) * syp2[q]; h += mk2(wb3) * s3y[q];                  \
            h.x = fmaxf(h.x, 0.f); h.y = fmaxf(h.y, 0.f);                     \
            dacc3[q] += mk2(u3) * h;                                          \
        }                                                                     \
    }                                                                         \
    _Pragma("unroll")                                                         \
    for (int q = 0; q < NC; ++q) {                                            \
        const int jp = CP0 + q;                                               \
        ldsP[lb + LOFF_X3 + jp] = packrtz(scl[q].x + dacc3[q].x,              \
                                          scl[q].y + dacc3[q].y);             \
    }                                                                         \
}

// premask: maxpool3(x0) > 0.1 as 17-bit per-lane mask (into `pmask`)
#define PREMASK                                                               \
{                                                                             \
    float rm[HW];                                                             \
    _Pragma("unroll")                                                         \
    for (int c = 0; c < HW; ++c) {                                            \
        float a  = (c >= 1)  ? EL(X0, c - 1) : 0.f;                           \
        float b2 = (c <= 15) ? EL(X0, c + 1) : 0.f;                           \
        rm[c] = max3f(a, EL(X0, c), b2);                                      \
    }                                                                         \
    pmask = 0u;                                                               \
    _Pragma("unroll")                                                         \
    for (int c = 0; c < HW; ++c) {                                            \
        float pm = max3f(rm[c], bperm(upA, rm[c]), bperm(dnA, rm[c]));        \
        pmask |= (pm > 0.1f) ? (1u << c) : 0u;                                \
    }                                                                         \
}

// all five pair-chunks + phantom-column reset
#define CHUNKS5                                                               \
{                                                                             \
    float vL0 = 0.f, dL0 = 0.f, vL1 = 0.f, dL1 = 0.f, vL2 = 0.f, dL2 = 0.f;   \
    CA_CHUNK(0, 2) CA_CHUNK(2, 4) CA_CHUNK(4, 6) CA_CHUNK(6, 8) CA_CHUNK(8, 9)\
    X0[8].y = 0.f; X1[8].y = 0.f; X2[8].y = 0.f;                              \
}

// post maxpool on ungated xn0 + life gate; W3!=0 also stores gated ch3 (final)
#define GATE(W3)                                                              \
{                                                                             \
    float rm[HW];                                                             \
    _Pragma("unroll")                                                         \
    for (int c = 0; c < HW; ++c) {                                            \
        float a  = (c >= 1)  ? EL(X0, c - 1) : 0.f;                           \
        float b2 = (c <= 15) ? EL(X0, c + 1) : 0.f;                           \
        rm[c] = max3f(a, EL(X0, c), b2);                                      \
    }                                                                         \
    _Pragma("unroll")                                                         \
    for (int c = 0; c < HW; ++c) {                                            \
        float pm = max3f(rm[c], bperm(upA, rm[c]), bperm(dnA, rm[c]));        \
        const bool L = ((pmask & (1u << c)) != 0u) && (pm > 0.1f);            \
        const float Lf = L ? 1.f : 0.f;                                       \
        EL(X0, c) = clampf(EL(X0, c)) * Lf;                                   \
        EL(X1, c) = clampf(EL(X1, c)) * Lf;                                   \
        EL(X2, c) = clampf(EL(X2, c)) * Lf;                                   \
        if (W3) {                                                             \
            const float2 p = __half22float2(u2h(ldsP[lb + LOFF_X3 + (c >> 1)])); \
            const float raw = (c & 1) ? p.y : p.x;                            \
            if (active) out_cell[cb + 3 * NPIX + c] = clampf(raw) * Lf;       \
        }                                                                     \
    }                                                                         \
}

__global__ __launch_bounds__(256)
void ca_kernel(const float* __restrict__ cell, const float* __restrict__ food,
               const float* __restrict__ w3, const float* __restrict__ b3,
               const float* __restrict__ w4, const float* __restrict__ b4,
               const int* __restrict__ steps_p, const int B,
               float* __restrict__ out_cell, float* __restrict__ out_food,
               float* __restrict__ out_cnt, float* __restrict__ out_abv)
{
    // per-thread private slots: [0,17) sxy fp16x2, [17,26) sc fp16 pairs,
    // [26,35) final-step xn3 fp16 pairs; stride 39 (odd -> conflict-free)
    __shared__ unsigned ldsP[256 * LSTRIDE];
    const int t    = threadIdx.x;
    const int lb   = t * LSTRIDE;
    const int lane = t & 63;
    const int wid  = blockIdx.x * (blockDim.x >> 6) + (t >> 6);
    const int bl   = lane / 17;                // 0..2 real, 3 dead
    const int r    = lane - bl * 17;
    const int batch = wid * 3 + bl;
    const bool active = (bl < 3) && (batch < B);
    const float am = active ? 1.f : 0.f;
    const f2 am2 = mk2(am);

    // vertical-neighbor shuffle addresses; out-of-range -> lane 63 (always zero)
    const int upA  = ((r >= 1)            ? (lane - 1) : 63) << 2;
    const int dnA  = ((r <= 15 && bl < 3) ? (lane + 1) : 63) << 2;
    const int up2A = ((r >= 2)            ? (lane - 2) : 63) << 2;
    const int dn2A = ((r <= 14 && bl < 3) ? (lane + 2) : 63) << 2;

    // ---- food load + copy-out ----
    const size_t fbase = (size_t)(active ? batch : 0) * NPIX + (size_t)r * HW;
    float f[HW];
    #pragma unroll
    for (int c = 0; c < HW; ++c) f[c] = active ? food[fbase + c] : 0.f;
    #pragma unroll
    for (int c = 0; c < HW; ++c) if (active) out_food[fbase + c] = f[c];

    // ---- scent (fp32), then pack to fp16 in LDS; scent-sobel likewise ----
    {
        float hf[HW];
        #pragma unroll
        for (int c = 0; c < HW; ++c) {
            float s = f[c];
            if (c >= 1)  s += 0.5f  * f[c - 1];
            if (c <= 15) s += 0.5f  * f[c + 1];
            if (c >= 2)  s += 0.25f * f[c - 2];
            if (c <= 14) s += 0.25f * f[c + 2];
            hf[c] = s;
        }
        float sc[HW];
        {
            float fu2[HW], fd2[HW];
            #pragma unroll
            for (int c = 0; c < HW; ++c) {
                float u1 = bperm(upA, hf[c]),  d1 = bperm(dnA, hf[c]);
                float u2 = bperm(up2A, hf[c]), d2 = bperm(dn2A, hf[c]);
                sc[c] = hf[c] + 0.5f * (u1 + d1) + 0.25f * (u2 + d2);
                fu2[c] = bperm(up2A, f[c]);
                fd2[c] = bperm(dn2A, f[c]);
            }
            #pragma unroll
            for (int c = 0; c < HW; ++c) {
                float corr = 0.f;
                if (c >= 2)  corr += fu2[c - 2] + fd2[c - 2];
                if (c <= 14) corr += fu2[c + 2] + fd2[c + 2];
                sc[c] = (sc[c] - 0.0625f * corr) * am;   // dead lanes exactly 0
            }
        }
        {
            float vS[HW + 2], dS[HW + 2];
            vS[0] = 0.f; vS[HW + 1] = 0.f; dS[0] = 0.f; dS[HW + 1] = 0.f;
            #pragma unroll
            for (int c = 0; c < HW; ++c) {
                float u = bperm(upA, sc[c]), d = bperm(dnA, sc[c]);
                vS[c + 1] = u + 2.f * sc[c] + d;
                dS[c + 1] = d - u;
            }
            #pragma unroll
            for (int c = 0; c < HW; ++c) {
                float sx3 = 0.125f * (vS[c + 2] - vS[c]);
                float sy3 = 0.125f * (dS[c] + 2.f * dS[c + 1] + dS[c + 2]);
                ldsP[lb + LOFF_SXY + c] = h2u(__floats2half2_rn(sx3, sy3));
            }
        }
        #pragma unroll
        for (int i = 0; i < 9; ++i)
            ldsP[lb + LOFF_SC + i] =
                h2u(__floats2half2_rn(sc[2 * i], (2 * i + 1 < HW) ? sc[2 * i + 1] : 0.f));
    }

    // ---- initial state as column pairs; column 17 is a phantom zero ----
    const size_t cb = (size_t)(active ? batch : 0) * (4 * NPIX) + (size_t)r * HW;
    f2 X0[9], X1[9], X2[9];
    #pragma unroll
    for (int c = 0; c < HW; ++c) {
        EL(X0, c) = active ? cell[cb + c] : 0.f;
        EL(X1, c) = active ? cell[cb + NPIX + c] : 0.f;
        EL(X2, c) = active ? cell[cb + 2 * NPIX + c] : 0.f;
    }
    X0[8].y = 0.f; X1[8].y = 0.f; X2[8].y = 0.f;

    const int steps = steps_p[0];
    unsigned pmask;

    // ---- main loop: all steps except the last (no ch3 anywhere) ----
    for (int s = 0; s < steps - 1; ++s) {
        PREMASK
        CHUNKS5
        GATE(0)
    }

    // ---- final step: ch3 pass (pre-update state) + normal step + gated ch3 store ----
    if (steps > 0) {
        PREMASK
        {
            float wL0 = 0.f, eL0 = 0.f, wL1 = 0.f, eL1 = 0.f, wL2 = 0.f, eL2 = 0.f;
            CH3_CHUNK(0, 2) CH3_CHUNK(2, 4) CH3_CHUNK(4, 6) CH3_CHUNK(6, 8) CH3_CHUNK(8, 9)
        }
        CHUNKS5
        GATE(1)
    }

    // ---- final outputs ----
    #pragma unroll
    for (int c = 0; c < HW; ++c) {
        if (active) {
            out_cell[cb + c]            = EL(X0, c);
            out_cell[cb + NPIX + c]     = EL(X1, c);
            out_cell[cb + 2 * NPIX + c] = EL(X2, c);
            if (steps == 0) out_cell[cb + 3 * NPIX + c] = cell[cb + 3 * NPIX + c];
        }
    }

    float rs = 0.f, rc = 0.f;
    #pragma unroll
    for (int c = 0; c < HW; ++c) {
        const float v = EL(X0, c);
        rs += v;
        rc += (v > 0.1f) ? 1.f : 0.f;
    }
    float ssum = rs, scnt = rc;
    for (int k = 1; k <= 16; ++k) {
        int a = ((lane + k) & 63) << 2;
        ssum += bperm(a, rs);
        scnt += bperm(a, rc);
    }
    if (active && r == 0) { out_cnt[batch] = ssum; out_abv[batch] = scnt; }
}

extern "C" void kernel_launch(void* const* d_in, const int* in_sizes, int n_in,
                              void* d_out, int out_size, void* d_ws, size_t ws_size,
                              hipStream_t stream) {
    const float* cell  = (const float*)d_in[0];
    const float* food  = (const float*)d_in[1];
    const float* w3    = (const float*)d_in[2];
    const float* b3    = (const float*)d_in[3];
    const float* w4    = (const float*)d_in[4];
    const float* b4    = (const float*)d_in[5];
    const int*   steps = (const int*)d_in[6];

    const int B = in_sizes[0] / (4 * NPIX);

    float* out      = (float*)d_out;
    float* out_cell = out;
    float* out_food = out      + (size_t)B * 4 * NPIX;
    float* out_cnt  = out_food + (size_t)B * NPIX;
    float* out_abv  = out_cnt  + (size_t)B;

    const int waves  = (B + 2) / 3;
    const int blocks = (waves + 3) / 4;
    hipLaunchKernelGGL(ca_kernel, dim3(blocks), dim3(256), 0, stream,
                       cell, food, w3, b3, w4, b4, steps, B,
                       out_cell, out_food, out_cnt, out_abv);
}

// Round 11
// 1877.893 us; speedup vs baseline: 1.3696x; 1.1770x over previous
//
#include <hip/hip_runtime.h>
#include <hip/hip_fp16.h>

#define HW 17
#define NPIX 289
#define LSTRIDE 35
#define LOFF_SXY 0
#define LOFF_SC  17
#define LOFF_X3  26

typedef float f2 __attribute__((ext_vector_type(2)));
typedef __fp16 h2v __attribute__((ext_vector_type(2)));

__device__ __forceinline__ float bperm(int a, float v) {
    return __int_as_float(__builtin_amdgcn_ds_bpermute(a, __float_as_int(v)));
}
__device__ __forceinline__ float max3f(float a, float b, float c){ return fmaxf(fmaxf(a,b),c); }
__device__ __forceinline__ float clampf(float v){ return __builtin_amdgcn_fmed3f(v, -10.f, 10.f); }
__device__ __forceinline__ f2 mk2(float s){ return (f2){s,s}; }
__device__ __forceinline__ unsigned h2u(__half2 h){ union{__half2 h; unsigned u;} v; v.h=h; return v.u; }
__device__ __forceinline__ __half2 u2h(unsigned u){ union{__half2 h; unsigned u;} v; v.u=u; return v.h; }
__device__ __forceinline__ unsigned packrtz(float a, float b){
    union{h2v h; unsigned u;} v; v.h = __builtin_amdgcn_cvt_pkrtz(a, b); return v.u;
}

#define EL(A,c) (A[(c)>>1][(c)&1])

// Sobel column windows (vertical sum v, diff d) for one channel over a
// pair-chunk; carries last needed column's v/d in (vL,dL). Cols >16 are 0.
#define SOBWIN(XA, vL, dL, sxp, syp)                                          \
    {                                                                         \
        float v[2*NC+2], d[2*NC+2];                                           \
        v[0] = (vL); d[0] = (dL);                                             \
        _Pragma("unroll")                                                     \
        for (int i = 1; i < 2*NC+2; ++i) {                                    \
            const int c = 2*CP0 - 1 + i;                                      \
            if (c <= 16) {                                                    \
                const float xv = EL(XA, c);                                   \
                const float u_ = bperm(upA, xv), dn_ = bperm(dnA, xv);        \
                v[i] = u_ + 2.f*xv + dn_; d[i] = dn_ - u_;                    \
            } else { v[i] = 0.f; d[i] = 0.f; }                                \
        }                                                                     \
        (vL) = v[2*NC]; (dL) = d[2*NC];                                       \
        _Pragma("unroll")                                                     \
        for (int q = 0; q < NC; ++q) {                                        \
            sxp[q] = (f2){ 0.125f*(v[2*q+2]-v[2*q]),                          \
                           0.125f*(v[2*q+3]-v[2*q+1]) };                      \
            syp[q] = (f2){ 0.125f*(d[2*q] + 2.f*d[2*q+1] + d[2*q+2]),         \
                           0.125f*(d[2*q+1] + 2.f*d[2*q+2] + d[2*q+3]) };     \
        }                                                                     \
    }

// Load per-lane fp16 constants for pair jp from private LDS slots.
#define LOAD_CONST(q, jp)                                                     \
        const float2 sf = __half22float2(u2h(ldsP[lb + LOFF_SC + (jp)]));     \
        scl[q] = (f2){ sf.x, sf.y };                                          \
        {                                                                     \
            const float2 a_ = __half22float2(u2h(ldsP[lb + LOFF_SXY + 2*(jp)])); \
            if (2*(jp) + 1 <= 16) {                                           \
                const float2 b_ = __half22float2(u2h(ldsP[lb + LOFF_SXY + 2*(jp) + 1])); \
                s3x[q] = (f2){ a_.x, b_.x }; s3y[q] = (f2){ a_.y, b_.y };     \
            } else {                                                          \
                s3x[q] = (f2){ a_.x, 0.f }; s3y[q] = (f2){ a_.y, 0.f };       \
            }                                                                 \
        }

// Main pair-chunk: sobel + packed dense (ch0..2 ONLY — ch3 is dead in the
// hot loop, handled once on the final step) + in-place state update.
#define CA_CHUNK(P0_, P1_)                                                    \
{                                                                             \
    constexpr int CP0 = (P0_);                                                \
    constexpr int NC  = (P1_) - (P0_);                                        \
    f2 sxp0[NC], syp0[NC], sxp1[NC], syp1[NC], sxp2[NC], syp2[NC];            \
    SOBWIN(X0, vL0, dL0, sxp0, syp0)                                          \
    SOBWIN(X1, vL1, dL1, sxp1, syp1)                                          \
    SOBWIN(X2, vL2, dL2, sxp2, syp2)                                          \
    f2 scl[NC], s3x[NC], s3y[NC];                                             \
    _Pragma("unroll")                                                         \
    for (int q = 0; q < NC; ++q) { LOAD_CONST(q, CP0 + q) }                   \
    f2 dacc0[NC], dacc1[NC], dacc2[NC];                                       \
    _Pragma("unroll")                                                         \
    for (int q = 0; q < NC; ++q) {                                            \
        dacc0[q] = mk2(b4[0]); dacc1[q] = mk2(b4[1]); dacc2[q] = mk2(b4[2]);  \
    }                                                                         \
    _Pragma("clang loop unroll_count(2)")                                     \
    for (int o = 0; o < 16; ++o) {                                            \
        const float wx0 = w3[o*12+0], wx1 = w3[o*12+1], wx2 = w3[o*12+2], wx3 = w3[o*12+3]; \
        const float wa0 = w3[o*12+4], wa1 = w3[o*12+5], wa2 = w3[o*12+6], wa3 = w3[o*12+7]; \
        const float wb0 = w3[o*12+8], wb1 = w3[o*12+9], wb2 = w3[o*12+10], wb3 = w3[o*12+11]; \
        const float bo = b3[o];                                               \
        const float u0 = w4[o], u1 = w4[16+o], u2 = w4[32+o];                 \
        _Pragma("unroll")                                                     \
        for (int q = 0; q < NC; ++q) {                                        \
            const int jp = CP0 + q;                                           \
            f2 h = mk2(bo);                                                   \
            h += mk2(wx0) * X0[jp];  h += mk2(wx1) * X1[jp];                  \
            h += mk2(wx2) * X2[jp];  h += mk2(wx3) * scl[q];                  \
            h += mk2(wa0) * sxp0[q]; h += mk2(wa1) * sxp1[q];                 \
            h += mk2(wa2) * sxp2[q]; h += mk2(wa3) * s3x[q];                  \
            h += mk2(wb0) * syp0[q]; h += mk2(wb1) * syp1[q];                 \
            h += mk2(wb2) * syp2[q]; h += mk2(wb3) * s3y[q];                  \
            h.x = fmaxf(h.x, 0.f); h.y = fmaxf(h.y, 0.f);                     \
            dacc0[q] += mk2(u0) * h; dacc1[q] += mk2(u1) * h;                 \
            dacc2[q] += mk2(u2) * h;                                          \
        }                                                                     \
    }                                                                         \
    _Pragma("unroll")                                                         \
    for (int q = 0; q < NC; ++q) {                                            \
        const int jp = CP0 + q;                                               \
        X0[jp] = (X0[jp] + dacc0[q]) * am2;                                   \
        X1[jp] = (X1[jp] + dacc1[q]) * am2;                                   \
        X2[jp] = (X2[jp] + dacc2[q]) * am2;                                   \
    }                                                                         \
}

// ch3-only pass (final step, BEFORE the state update): full h chain but only
// dacc3; ungated xn3 packed to private LDS. Runs once per kernel (cold).
#define CH3_CHUNK(P0_, P1_)                                                   \
{                                                                             \
    constexpr int CP0 = (P0_);                                                \
    constexpr int NC  = (P1_) - (P0_);                                        \
    f2 sxp0[NC], syp0[NC], sxp1[NC], syp1[NC], sxp2[NC], syp2[NC];            \
    SOBWIN(X0, wL0, eL0, sxp0, syp0)                                          \
    SOBWIN(X1, wL1, eL1, sxp1, syp1)                                          \
    SOBWIN(X2, wL2, eL2, sxp2, syp2)                                          \
    f2 scl[NC], s3x[NC], s3y[NC];                                             \
    _Pragma("unroll")                                                         \
    for (int q = 0; q < NC; ++q) { LOAD_CONST(q, CP0 + q) }                   \
    f2 dacc3[NC];                                                             \
    _Pragma("unroll")                                                         \
    for (int q = 0; q < NC; ++q) dacc3[q] = mk2(b4[3]);                       \
    for (int o = 0; o < 16; ++o) {                                            \
        const float wx0 = w3[o*12+0], wx1 = w3[o*12+1], wx2 = w3[o*12+2], wx3 = w3[o*12+3]; \
        const float wa0 = w3[o*12+4], wa1 = w3[o*12+5], wa2 = w3[o*12+6], wa3 = w3[o*12+7]; \
        const float wb0 = w3[o*12+8], wb1 = w3[o*12+9], wb2 = w3[o*12+10], wb3 = w3[o*12+11]; \
        const float bo = b3[o];                                               \
        const float u3 = w4[48+o];                                            \
        _Pragma("unroll")                                                     \
        for (int q = 0; q < NC; ++q) {                                        \
            const int jp = CP0 + q;                                           \
            f2 h = mk2(bo);                                                   \
            h += mk2(wx0) * X0[jp];  h += mk2(wx1) * X1[jp];                  \
            h += mk2(wx2) * X2[jp];  h += mk2(wx3) * scl[q];                  \
            h += mk2(wa0) * sxp0[q]; h += mk2(wa1) * sxp1[q];                 \
            h += mk2(wa2) * sxp2[q]; h += mk2(wa3) * s3x[q];                  \
            h += mk2(wb0) * syp0[q]; h += mk2(wb1) * syp1[q];                 \
            h += mk2(wb2) * syp2[q]; h += mk2(wb3) * s3y[q];                  \
            h.x = fmaxf(h.x, 0.f); h.y = fmaxf(h.y, 0.f);                     \
            dacc3[q] += mk2(u3) * h;                                          \
        }                                                                     \
    }                                                                         \
    _Pragma("unroll")                                                         \
    for (int q = 0; q < NC; ++q) {                                            \
        const int jp = CP0 + q;                                               \
        ldsP[lb + LOFF_X3 + jp] = packrtz(scl[q].x + dacc3[q].x,              \
                                          scl[q].y + dacc3[q].y);             \
    }                                                                         \
}

// premask: maxpool3(x0) > 0.1 as 17-bit per-lane mask (into `pmask`)
#define PREMASK                                                               \
{                                                                             \
    float rm[HW];                                                             \
    _Pragma("unroll")                                                         \
    for (int c = 0; c < HW; ++c) {                                            \
        float a  = (c >= 1)  ? EL(X0, c - 1) : 0.f;                           \
        float b2 = (c <= 15) ? EL(X0, c + 1) : 0.f;                           \
        rm[c] = max3f(a, EL(X0, c), b2);                                      \
    }                                                                         \
    pmask = 0u;                                                               \
    _Pragma("unroll")                                                         \
    for (int c = 0; c < HW; ++c) {                                            \
        float pm = max3f(rm[c], bperm(upA, rm[c]), bperm(dnA, rm[c]));        \
        pmask |= (pm > 0.1f) ? (1u << c) : 0u;                                \
    }                                                                         \
}

// all three pair-chunks + phantom-column reset (round-5 partition)
#define CHUNKS3                                                               \
{                                                                             \
    float vL0 = 0.f, dL0 = 0.f, vL1 = 0.f, dL1 = 0.f, vL2 = 0.f, dL2 = 0.f;   \
    CA_CHUNK(0, 3) CA_CHUNK(3, 6) CA_CHUNK(6, 9)                              \
    X0[8].y = 0.f; X1[8].y = 0.f; X2[8].y = 0.f;                              \
}

// post maxpool on ungated xn0 + life gate; W3!=0 also stores gated ch3 (final)
#define GATE(W3)                                                              \
{                                                                             \
    float rm[HW];                                                             \
    _Pragma("unroll")                                                         \
    for (int c = 0; c < HW; ++c) {                                            \
        float a  = (c >= 1)  ? EL(X0, c - 1) : 0.f;                           \
        float b2 = (c <= 15) ? EL(X0, c + 1) : 0.f;                           \
        rm[c] = max3f(a, EL(X0, c), b2);                                      \
    }                                                                         \
    _Pragma("unroll")                                                         \
    for (int c = 0; c < HW; ++c) {                                            \
        float pm = max3f(rm[c], bperm(upA, rm[c]), bperm(dnA, rm[c]));        \
        const bool L = ((pmask & (1u << c)) != 0u) && (pm > 0.1f);            \
        const float Lf = L ? 1.f : 0.f;                                       \
        EL(X0, c) = clampf(EL(X0, c)) * Lf;                                   \
        EL(X1, c) = clampf(EL(X1, c)) * Lf;                                   \
        EL(X2, c) = clampf(EL(X2, c)) * Lf;                                   \
        if (W3) {                                                             \
            const float2 p = __half22float2(u2h(ldsP[lb + LOFF_X3 + (c >> 1)])); \
            const float raw = (c & 1) ? p.y : p.x;                            \
            if (active) out_cell[cb + 3 * NPIX + c] = clampf(raw) * Lf;       \
        }                                                                     \
    }                                                                         \
}

__global__ __launch_bounds__(256)
void ca_kernel(const float* __restrict__ cell, const float* __restrict__ food,
               const float* __restrict__ w3, const float* __restrict__ b3,
               const float* __restrict__ w4, const float* __restrict__ b4,
               const int* __restrict__ steps_p, const int B,
               float* __restrict__ out_cell, float* __restrict__ out_food,
               float* __restrict__ out_cnt, float* __restrict__ out_abv)
{
    // per-thread private slots: [0,17) sxy fp16x2, [17,26) sc fp16 pairs,
    // [26,35) final-step xn3 fp16 pairs; stride 35 (odd -> conflict-free)
    __shared__ unsigned ldsP[256 * LSTRIDE];
    const int t    = threadIdx.x;
    const int lb   = t * LSTRIDE;
    const int lane = t & 63;
    const int wid  = blockIdx.x * (blockDim.x >> 6) + (t >> 6);
    const int bl   = lane / 17;                // 0..2 real, 3 dead
    const int r    = lane - bl * 17;
    const int batch = wid * 3 + bl;
    const bool active = (bl < 3) && (batch < B);
    const float am = active ? 1.f : 0.f;
    const f2 am2 = mk2(am);

    // vertical-neighbor shuffle addresses; out-of-range -> lane 63 (always zero)
    const int upA  = ((r >= 1)            ? (lane - 1) : 63) << 2;
    const int dnA  = ((r <= 15 && bl < 3) ? (lane + 1) : 63) << 2;
    const int up2A = ((r >= 2)            ? (lane - 2) : 63) << 2;
    const int dn2A = ((r <= 14 && bl < 3) ? (lane + 2) : 63) << 2;

    // ---- food load + copy-out ----
    const size_t fbase = (size_t)(active ? batch : 0) * NPIX + (size_t)r * HW;
    float f[HW];
    #pragma unroll
    for (int c = 0; c < HW; ++c) f[c] = active ? food[fbase + c] : 0.f;
    #pragma unroll
    for (int c = 0; c < HW; ++c) if (active) out_food[fbase + c] = f[c];

    // ---- scent (fp32), then pack to fp16 in LDS; scent-sobel likewise ----
    {
        float hf[HW];
        #pragma unroll
        for (int c = 0; c < HW; ++c) {
            float s = f[c];
            if (c >= 1)  s += 0.5f  * f[c - 1];
            if (c <= 15) s += 0.5f  * f[c + 1];
            if (c >= 2)  s += 0.25f * f[c - 2];
            if (c <= 14) s += 0.25f * f[c + 2];
            hf[c] = s;
        }
        float sc[HW];
        {
            float fu2[HW], fd2[HW];
            #pragma unroll
            for (int c = 0; c < HW; ++c) {
                float u1 = bperm(upA, hf[c]),  d1 = bperm(dnA, hf[c]);
                float u2 = bperm(up2A, hf[c]), d2 = bperm(dn2A, hf[c]);
                sc[c] = hf[c] + 0.5f * (u1 + d1) + 0.25f * (u2 + d2);
                fu2[c] = bperm(up2A, f[c]);
                fd2[c] = bperm(dn2A, f[c]);
            }
            #pragma unroll
            for (int c = 0; c < HW; ++c) {
                float corr = 0.f;
                if (c >= 2)  corr += fu2[c - 2] + fd2[c - 2];
                if (c <= 14) corr += fu2[c + 2] + fd2[c + 2];
                sc[c] = (sc[c] - 0.0625f * corr) * am;   // dead lanes exactly 0
            }
        }
        {
            float vS[HW + 2], dS[HW + 2];
            vS[0] = 0.f; vS[HW + 1] = 0.f; dS[0] = 0.f; dS[HW + 1] = 0.f;
            #pragma unroll
            for (int c = 0; c < HW; ++c) {
                float u = bperm(upA, sc[c]), d = bperm(dnA, sc[c]);
                vS[c + 1] = u + 2.f * sc[c] + d;
                dS[c + 1] = d - u;
            }
            #pragma unroll
            for (int c = 0; c < HW; ++c) {
                float sx3 = 0.125f * (vS[c + 2] - vS[c]);
                float sy3 = 0.125f * (dS[c] + 2.f * dS[c + 1] + dS[c + 2]);
                ldsP[lb + LOFF_SXY + c] = h2u(__floats2half2_rn(sx3, sy3));
            }
        }
        #pragma unroll
        for (int i = 0; i < 9; ++i)
            ldsP[lb + LOFF_SC + i] =
                h2u(__floats2half2_rn(sc[2 * i], (2 * i + 1 < HW) ? sc[2 * i + 1] : 0.f));
    }

    // ---- initial state as column pairs; column 17 is a phantom zero ----
    const size_t cb = (size_t)(active ? batch : 0) * (4 * NPIX) + (size_t)r * HW;
    f2 X0[9], X1[9], X2[9];
    #pragma unroll
    for (int c = 0; c < HW; ++c) {
        EL(X0, c) = active ? cell[cb + c] : 0.f;
        EL(X1, c) = active ? cell[cb + NPIX + c] : 0.f;
        EL(X2, c) = active ? cell[cb + 2 * NPIX + c] : 0.f;
    }
    X0[8].y = 0.f; X1[8].y = 0.f; X2[8].y = 0.f;

    const int steps = steps_p[0];
    unsigned pmask;

    // ---- main loop: all steps except the last (no ch3 anywhere) ----
    for (int s = 0; s < steps - 1; ++s) {
        PREMASK
        CHUNKS3
        GATE(0)
    }

    // ---- final step: ch3 pass (pre-update state) + normal step + gated ch3 store ----
    if (steps > 0) {
        PREMASK
        {
            float wL0 = 0.f, eL0 = 0.f, wL1 = 0.f, eL1 = 0.f, wL2 = 0.f, eL2 = 0.f;
            CH3_CHUNK(0, 3) CH3_CHUNK(3, 6) CH3_CHUNK(6, 9)
        }
        CHUNKS3
        GATE(1)
    }

    // ---- final outputs ----
    #pragma unroll
    for (int c = 0; c < HW; ++c) {
        if (active) {
            out_cell[cb + c]            = EL(X0, c);
            out_cell[cb + NPIX + c]     = EL(X1, c);
            out_cell[cb + 2 * NPIX + c] = EL(X2, c);
            if (steps == 0) out_cell[cb + 3 * NPIX + c] = cell[cb + 3 * NPIX + c];
        }
    }

    float rs = 0.f, rc = 0.f;
    #pragma unroll
    for (int c = 0; c < HW; ++c) {
        const float v = EL(X0, c);
        rs += v;
        rc += (v > 0.1f) ? 1.f : 0.f;
    }
    float ssum = rs, scnt = rc;
    for (int k = 1; k <= 16; ++k) {
        int a = ((lane + k) & 63) << 2;
        ssum += bperm(a, rs);
        scnt += bperm(a, rc);
    }
    if (active && r == 0) { out_cnt[batch] = ssum; out_abv[batch] = scnt; }
}

extern "C" void kernel_launch(void* const* d_in, const int* in_sizes, int n_in,
                              void* d_out, int out_size, void* d_ws, size_t ws_size,
                              hipStream_t stream) {
    const float* cell  = (const float*)d_in[0];
    const float* food  = (const float*)d_in[1];
    const float* w3    = (const float*)d_in[2];
    const float* b3    = (const float*)d_in[3];
    const float* w4    = (const float*)d_in[4];
    const float* b4    = (const float*)d_in[5];
    const int*   steps = (const int*)d_in[6];

    const int B = in_sizes[0] / (4 * NPIX);

    float* out      = (float*)d_out;
    float* out_cell = out;
    float* out_food = out      + (size_t)B * 4 * NPIX;
    float* out_cnt  = out_food + (size_t)B * NPIX;
    float* out_abv  = out_cnt  + (size_t)B;

    const int waves  = (B + 2) / 3;
    const int blocks = (waves + 3) / 4;
    hipLaunchKernelGGL(ca_kernel, dim3(blocks), dim3(256), 0, stream,
                       cell, food, w3, b3, w4, b4, steps, B,
                       out_cell, out_food, out_cnt, out_abv);
}